// Round 3
// baseline (302.183 us; speedup 1.0000x reference)
//
#include <hip/hip_runtime.h>

// Problem constants (from reference): B=16, S=4096, D=256, MAXDUR=8
#define BATCH 16
#define SEQ   4096
#define DIM   256

typedef float f32x4 __attribute__((ext_vector_type(4)));

// ---------------------------------------------------------------------------
// Kernel A: per-batch inclusive scan of durations -> csum/totals, plus
// (gather mode) scatter of source-row id into idx[B][T] and tail -1 fill.
// One block per batch; 1024 threads * 4 elements = 4096.
// idx != nullptr  -> gather mode: write idx, skip csum
// idx == nullptr  -> fallback mode: write csum for the scatter kernel
// ---------------------------------------------------------------------------
__global__ __launch_bounds__(1024) void scan_kernel(const int* __restrict__ dims,
                                                    int* __restrict__ csum,
                                                    int* __restrict__ totals,
                                                    int* __restrict__ idx,
                                                    int T) {
    __shared__ int wsum[16];
    __shared__ int stot;
    const int b    = blockIdx.x;
    const int tid  = threadIdx.x;      // 0..1023
    const int lane = tid & 63;
    const int wave = tid >> 6;         // 0..15

    // 4 consecutive durations per thread (int4, 16B aligned)
    const int4 dv = ((const int4*)(dims + b * SEQ))[tid];
    const int p0 = dv.x;
    const int p1 = p0 + dv.y;
    const int p2 = p1 + dv.z;
    const int p3 = p2 + dv.w;          // thread-local inclusive sums
    int v = p3;                        // thread total

    // wave-level inclusive scan of thread totals (64 lanes)
    #pragma unroll
    for (int off = 1; off < 64; off <<= 1) {
        int n = __shfl_up(v, off, 64);
        if (lane >= off) v += n;
    }
    if (lane == 63) wsum[wave] = v;    // wave total
    __syncthreads();

    if (tid == 0) {                    // serial exclusive scan over 16 wave totals
        int run = 0;
        #pragma unroll
        for (int i = 0; i < 16; ++i) { int t = wsum[i]; wsum[i] = run; run += t; }
        totals[b] = run;               // full batch total
        stot      = run;
    }
    __syncthreads();

    const int excl = wsum[wave] + (v - p3);   // block-exclusive prefix of this thread

    if (idx) {
        // gather mode: idx[b][k] = s for k in [start(s), end(s)); tail = -1
        int* __restrict__ ib = idx + (size_t)b * T;
        const int s0 = tid * 4;
        const int st0 = excl,      en0 = excl + p0;
        const int st1 = en0,       en1 = excl + p1;
        const int st2 = en1,       en2 = excl + p2;
        const int st3 = en2,       en3 = excl + p3;
        for (int k = st0; k < en0; ++k) ib[k] = s0;
        for (int k = st1; k < en1; ++k) ib[k] = s0 + 1;
        for (int k = st2; k < en2; ++k) ib[k] = s0 + 2;
        for (int k = st3; k < en3; ++k) ib[k] = s0 + 3;
        for (int t = stot + tid; t < T; t += 1024) ib[t] = -1;  // tail marker
    } else {
        // fallback mode: inclusive csum for the scatter kernel
        int4 o;
        o.x = excl + p0; o.y = excl + p1; o.z = excl + p2; o.w = excl + p3;
        ((int4*)(csum + b * SEQ))[tid] = o;
    }
}

// ---------------------------------------------------------------------------
// Kernel B (gather): one wave per OUTPUT row. Always exactly 1 load + 1
// store per wave — dense sequential write stream identical in shape to the
// runtime's fillBuffer (which sustains 6.4 TB/s). idx<0 rows (tail) store
// zeros, so no separate tail pass. x reads hit L2: avg 3.5 consecutive
// output rows share one source row and map to adjacent waves/blocks.
// R1 lesson: stores CACHED (nt stores cost +8.5us). Loads cached too (reuse).
// ---------------------------------------------------------------------------
__global__ __launch_bounds__(256) void gather_kernel(const float* __restrict__ x,
                                                     const int* __restrict__ idx,
                                                     float* __restrict__ out,
                                                     int T) {
    const int lane = threadIdx.x & 63;
    const int wave = threadIdx.x >> 6;
    const int b    = blockIdx.y;
    const int t    = blockIdx.x * 4 + wave;
    if (t >= T) return;

    const int s = idx[(size_t)b * T + t];            // 4B broadcast load
    f32x4* dst = (f32x4*)out + ((size_t)b * T + t) * (DIM / 4) + lane;
    if (s < 0) {
        const f32x4 z = {0.f, 0.f, 0.f, 0.f};
        *dst = z;
        return;
    }
    const f32x4 row = ((const f32x4*)x)[((size_t)b * SEQ + s) * (DIM / 4) + lane];
    *dst = row;
}

// ---------------------------------------------------------------------------
// Kernel B (fallback scatter, R1 exact): one wave per source row, cached
// stores, predicated 7-way store fan-out. Used only if ws is too small for
// the idx map.
// ---------------------------------------------------------------------------
#define SCATTER_BLOCKS (BATCH * SEQ / 4)
#define TAILC 128

__global__ __launch_bounds__(256) void expand_kernel(const float* __restrict__ x,
                                                     const int* __restrict__ csum,
                                                     const int* __restrict__ totals,
                                                     float* __restrict__ out,
                                                     int T) {
    const int lane = threadIdx.x & 63;
    const int wave = threadIdx.x >> 6;

    if (blockIdx.x < SCATTER_BLOCKS) {
        const int wv  = blockIdx.x * 4 + wave;
        const int b   = wv >> 12;
        const int s   = wv & (SEQ - 1);

        int start, end;
        if (s != 0) {
            const int2 se = *(const int2*)(csum + wv - 1);
            start = se.x; end = se.y;
        } else {
            start = 0;   end = csum[wv];
        }
        const int cnt = end - start;
        if (cnt <= 0) return;

        const f32x4 row = __builtin_nontemporal_load(
            ((const f32x4*)x) + (size_t)wv * (DIM / 4) + lane);
        f32x4* dst = (f32x4*)out + ((size_t)b * T + start) * (DIM / 4) + lane;

        #pragma unroll
        for (int j = 0; j < 7; ++j) {
            if (j < cnt) dst[j * (DIM / 4)] = row;
        }
        for (int j = 7; j < cnt; ++j)
            dst[j * (DIM / 4)] = row;
    } else {
        const int idx   = blockIdx.x - SCATTER_BLOCKS;
        const int b     = idx / TAILC;
        const int chunk = idx % TAILC;
        const int t0    = totals[b];
        const f32x4 z   = {0.f, 0.f, 0.f, 0.f};
        for (int t = t0 + chunk * 4 + wave; t < T; t += 2 * TAILC * 4) {
            ((f32x4*)out)[((size_t)b * T + t) * (DIM / 4) + lane] = z;
            const int t2 = t + TAILC * 4;
            if (t2 < T)
                ((f32x4*)out)[((size_t)b * T + t2) * (DIM / 4) + lane] = z;
        }
    }
}

extern "C" void kernel_launch(void* const* d_in, const int* in_sizes, int n_in,
                              void* d_out, int out_size, void* d_ws, size_t ws_size,
                              hipStream_t stream) {
    const float* x    = (const float*)d_in[0];   // [B,S,D] float32
    const int*   dims = (const int*)d_in[1];     // [B,S,1] int32
    float*       out  = (float*)d_out;           // [B,T,D] float32

    const int T = out_size / (BATCH * DIM * (int)sizeof(float)) > 0
                    ? out_size / (BATCH * DIM * (int)sizeof(float))
                    : out_size / (BATCH * DIM);
    // out_size is in bytes in this harness (matches previous rounds' use where
    // out_size/(BATCH*DIM) gave T in float units); keep the original formula:
    const int Tf = out_size / (BATCH * DIM);     // as used (and verified) in R0-R2

    int* totals = (int*)d_ws;                    // 64 ints (256B, keeps alignment)
    int* csum   = totals + 64;                   // B*S ints
    int* idxmap = csum + BATCH * SEQ;            // B*T ints (gather mode)

    const size_t need = (size_t)(64 + BATCH * SEQ) * 4 + (size_t)BATCH * Tf * 4;

    if (ws_size >= need) {
        scan_kernel<<<BATCH, 1024, 0, stream>>>(dims, csum, totals, idxmap, Tf);
        dim3 grid((Tf + 3) / 4, BATCH);
        gather_kernel<<<grid, 256, 0, stream>>>(x, idxmap, out, Tf);
    } else {
        scan_kernel<<<BATCH, 1024, 0, stream>>>(dims, csum, totals, nullptr, Tf);
        expand_kernel<<<SCATTER_BLOCKS + BATCH * TAILC, 256, 0, stream>>>(
            x, csum, totals, out, Tf);
    }
    (void)T;
}